// Round 1
// baseline (266.157 us; speedup 1.0000x reference)
//
#include <hip/hip_runtime.h>

typedef unsigned short u16;
typedef __bf16 bf16x8 __attribute__((ext_vector_type(8)));
typedef float f32x4 __attribute__((ext_vector_type(4)));
typedef u16 u16x4 __attribute__((ext_vector_type(4)));
typedef u16 u16x8 __attribute__((ext_vector_type(8)));

#define EPS 1e-5f

__device__ __forceinline__ u16 f2bf(float f) {
  unsigned u = __builtin_bit_cast(unsigned, f);
  u += 0x7FFFu + ((u >> 16) & 1u);   // RNE
  return (u16)(u >> 16);
}
__device__ __forceinline__ float bf2f(u16 h) {
  unsigned u = ((unsigned)h) << 16;
  return __builtin_bit_cast(float, u);
}

// ---------------- weight prep: fold BN scale into bf16 weights ----------------
__global__ void prep_weights(
    const float* __restrict__ wa, const float* __restrict__ g1, const float* __restrict__ b1,
    const float* __restrict__ m1, const float* __restrict__ v1,
    const float* __restrict__ w1, const float* __restrict__ g2, const float* __restrict__ b2,
    const float* __restrict__ m2, const float* __restrict__ v2,
    const float* __restrict__ w2,
    u16* __restrict__ wa_o, u16* __restrict__ w1_o, u16* __restrict__ w2_o,
    float* __restrict__ bias1, float* __restrict__ bias2) {
  int t = blockIdx.x * 256 + threadIdx.x;
  if (t < 256 * 256) {
    int m = t >> 8;
    float s = g1[m] / sqrtf(v1[m] + EPS);
    wa_o[t] = f2bf(wa[t] * s);
  }
  if (t < 128 * 256) {
    int m = t >> 8;
    float s = g2[m] / sqrtf(v2[m] + EPS);
    w1_o[t] = f2bf(w1[t] * s);
  }
  if (t < 256 * 128) w2_o[t] = f2bf(w2[t]);
  if (t < 256) bias1[t] = b1[t] - m1[t] * (g1[t] / sqrtf(v1[t] + EPS));
  if (t < 128) bias2[t] = b2[t] - m2[t] * (g2[t] / sqrtf(v2[t] + EPS));
}

// ---------------- offset gen: grouped 3x3 conv + SiLU + 1x1 conv -> (ix,iy) ----------------
// block = 16x16 pixel tile of one image; grid = (4,4,16)
__global__ __launch_bounds__(256) void offsets_kernel(
    const float* __restrict__ xl, const float* __restrict__ w1,
    const float* __restrict__ w2, const float* __restrict__ b2,
    float* __restrict__ coords) {
  __shared__ float sw1[64 * 36];
  __shared__ float sw2[128];
  __shared__ float tile[4 * 18 * 18];
  int tid = threadIdx.x;
  int b = blockIdx.z;
  int ty0 = blockIdx.y * 16, tx0 = blockIdx.x * 16;
  for (int i = tid; i < 64 * 36; i += 256) sw1[i] = w1[i];
  if (tid < 128) sw2[tid] = w2[tid];
  int py = tid >> 4, px = tid & 15;
  int y = ty0 + py, x = tx0 + px;
  const float* xb = xl + (size_t)b * 256 * 4096;
  float ax = 0.f, ay = 0.f;
  for (int q = 0; q < 64; ++q) {
    for (int i = tid; i < 4 * 18 * 18; i += 256) {
      int ci = i / 324;
      int rem = i - ci * 324;
      int r = rem / 18, cc = rem - r * 18;
      int gy = ty0 - 1 + r, gx = tx0 - 1 + cc;
      float v = 0.f;
      if ((unsigned)gy < 64u && (unsigned)gx < 64u)
        v = xb[(size_t)(4 * q + ci) * 4096 + gy * 64 + gx];
      tile[i] = v;
    }
    __syncthreads();
    float s = 0.f;
    const float* wq = &sw1[q * 36];
#pragma unroll
    for (int ci = 0; ci < 4; ++ci)
#pragma unroll
      for (int dy = 0; dy < 3; ++dy)
#pragma unroll
        for (int dx = 0; dx < 3; ++dx)
          s += wq[ci * 9 + dy * 3 + dx] * tile[ci * 324 + (py + dy) * 18 + (px + dx)];
    float sl = s / (1.f + __expf(-s));  // SiLU
    ax += sw2[q] * sl;
    ay += sw2[64 + q] * sl;
    __syncthreads();
  }
  ax += b2[0];
  ay += b2[1];
  // ix = 64x/63 + off_x - 0.5  (align_corners=False, grid scale 2/64)
  float ix = (64.f / 63.f) * (float)x + ax - 0.5f;
  float iy = (64.f / 63.f) * (float)y + ay - 0.5f;
  int p = y * 64 + x;
  ((float2*)coords)[(size_t)b * 4096 + p] = make_float2(ix, iy);
}

// ---------------- templated MFMA GEMM ----------------
// BM=BN=128, BK=32, 256 threads = 4 waves, each wave owns a 64x64 quadrant (4x4 frags of 16x16x32).
// A: [Mtot][K] bf16 (pre-scaled weights). B: per-batch [K][4096] (f32 or bf16) -> LDS transposed [n][k].
// EPI 0: +bias1 -> g (bf16). EPI 1: +bias2, GELU -> h (bf16). EPI 2: bilinear-sample(g) + acc, SiLU -> out f32.
template <int K, bool B_IS_BF16, int EPI>
__global__ __launch_bounds__(256, 2) void gemm_k(
    const u16* __restrict__ A, const void* __restrict__ Bsrc,
    u16* __restrict__ OutBf, const float* __restrict__ bias,
    const u16* __restrict__ g, const float* __restrict__ coords,
    float* __restrict__ out_f) {
  __shared__ u16 Al[128][40];  // 32 data + 8 pad (row = 80B, 16B-aligned)
  __shared__ u16 Bl[128][40];  // [n][k]
  const int tid = threadIdx.x;
  const int b = blockIdx.z;
  const int n0 = blockIdx.x * 128;
  const int m0 = blockIdx.y * 128;
  const int wave = tid >> 6, lane = tid & 63;
  const int wr = wave >> 1, wc = wave & 1;
  const int lr = lane & 15, kg = lane >> 4;

  f32x4 acc[4][4] = {};

  const float* Bf = (const float*)Bsrc + (size_t)b * K * 4096;
  const u16* Bh = (const u16*)Bsrc + (size_t)b * K * 4096;

  for (int kt = 0; kt < K / 32; ++kt) {
    // ---- stage A (bf16, already converted) : 512 chunks of 8 bf16 ----
#pragma unroll
    for (int c = 0; c < 2; ++c) {
      int ch = tid + c * 256;
      int m = ch >> 2, pos = (ch & 3) * 8;
      u16x8 v = *(const u16x8*)(A + (size_t)(m0 + m) * K + kt * 32 + pos);
      *(u16x8*)&Al[m][pos] = v;
    }
    // ---- stage B with transpose (4x4 micro-tile per thread) ----
    {
      int nq = tid & 31, kq = tid >> 5;  // nq in [0,32), kq in [0,8)
      int kb = kt * 32 + kq * 4;
      int nb = n0 + nq * 4;
      if (B_IS_BF16) {
        u16x4 r[4];
#pragma unroll
        for (int i = 0; i < 4; ++i)
          r[i] = *(const u16x4*)(Bh + (size_t)(kb + i) * 4096 + nb);
#pragma unroll
        for (int j = 0; j < 4; ++j) {
          u16x4 w = {r[0][j], r[1][j], r[2][j], r[3][j]};
          *(u16x4*)&Bl[nq * 4 + j][kq * 4] = w;
        }
      } else {
        f32x4 r[4];
#pragma unroll
        for (int i = 0; i < 4; ++i)
          r[i] = *(const f32x4*)(Bf + (size_t)(kb + i) * 4096 + nb);
#pragma unroll
        for (int j = 0; j < 4; ++j) {
          u16x4 w = {f2bf(r[0][j]), f2bf(r[1][j]), f2bf(r[2][j]), f2bf(r[3][j])};
          *(u16x4*)&Bl[nq * 4 + j][kq * 4] = w;
        }
      }
    }
    __syncthreads();
    bf16x8 af[4], bfr[4];
#pragma unroll
    for (int i = 0; i < 4; ++i) {
      af[i] = *(const bf16x8*)&Al[wr * 64 + i * 16 + lr][kg * 8];
      bfr[i] = *(const bf16x8*)&Bl[wc * 64 + i * 16 + lr][kg * 8];
    }
#pragma unroll
    for (int i = 0; i < 4; ++i)
#pragma unroll
      for (int j = 0; j < 4; ++j)
        acc[i][j] = __builtin_amdgcn_mfma_f32_16x16x32_bf16(af[i], bfr[j], acc[i][j], 0, 0, 0);
    __syncthreads();
  }

  // ---- epilogue ----
  if constexpr (EPI == 0 || EPI == 1) {
    const int MT = (EPI == 0) ? 256 : 128;
    u16* O = OutBf + (size_t)b * MT * 4096;
#pragma unroll
    for (int i = 0; i < 4; ++i) {
      int rb = m0 + wr * 64 + i * 16 + kg * 4;
      f32x4 b4 = *(const f32x4*)(bias + rb);
#pragma unroll
      for (int j = 0; j < 4; ++j) {
        int col = n0 + wc * 64 + j * 16 + lr;
#pragma unroll
        for (int e = 0; e < 4; ++e) {
          float v = acc[i][j][e] + b4[e];
          if (EPI == 1) v = 0.5f * v * (1.f + erff(v * 0.70710678118f));  // exact GELU
          O[(size_t)(rb + e) * 4096 + col] = f2bf(v);
        }
      }
    }
  } else {
    const u16* gb = g + (size_t)b * 256 * 4096;
    float* Ob = out_f + (size_t)b * 256 * 4096;
#pragma unroll
    for (int j = 0; j < 4; ++j) {
      int col = n0 + wc * 64 + j * 16 + lr;
      float2 cd = ((const float2*)coords)[(size_t)b * 4096 + col];
      float ix = cd.x, iy = cd.y;
      float x0f = floorf(ix), y0f = floorf(iy);
      int x0 = (int)x0f, y0 = (int)y0f;
      float wx1 = ix - x0f, wx0 = 1.f - wx1;
      float wy1 = iy - y0f, wy0 = 1.f - wy1;
      bool vx0 = (unsigned)x0 < 64u, vx1 = (unsigned)(x0 + 1) < 64u;
      bool vy0 = (unsigned)y0 < 64u, vy1 = (unsigned)(y0 + 1) < 64u;
      int x0c = min(max(x0, 0), 63), x1c = min(max(x0 + 1, 0), 63);
      int y0c = min(max(y0, 0), 63), y1c = min(max(y0 + 1, 0), 63);
      float w00 = (vx0 && vy0) ? wx0 * wy0 : 0.f;
      float w10 = (vx1 && vy0) ? wx1 * wy0 : 0.f;
      float w01 = (vx0 && vy1) ? wx0 * wy1 : 0.f;
      float w11 = (vx1 && vy1) ? wx1 * wy1 : 0.f;
      int i00 = y0c * 64 + x0c, i10 = y0c * 64 + x1c;
      int i01 = y1c * 64 + x0c, i11 = y1c * 64 + x1c;
#pragma unroll
      for (int i = 0; i < 4; ++i) {
        int rb = m0 + wr * 64 + i * 16 + kg * 4;
#pragma unroll
        for (int e = 0; e < 4; ++e) {
          int c = rb + e;
          const u16* gc = gb + (size_t)c * 4096;
          float samp = w00 * bf2f(gc[i00]) + w10 * bf2f(gc[i10]) +
                       w01 * bf2f(gc[i01]) + w11 * bf2f(gc[i11]);
          float v = samp + acc[i][j][e];
          Ob[(size_t)c * 4096 + col] = v / (1.f + __expf(-v));  // SiLU
        }
      }
    }
  }
}

// ---------------- launch ----------------
extern "C" void kernel_launch(void* const* d_in, const int* in_sizes, int n_in,
                              void* d_out, int out_size, void* d_ws, size_t ws_size,
                              hipStream_t stream) {
  const float* x_local = (const float*)d_in[0];
  const float* x_guide = (const float*)d_in[1];
  const float* w_align = (const float*)d_in[2];
  const float* bn1_g = (const float*)d_in[3];
  const float* bn1_b = (const float*)d_in[4];
  const float* bn1_m = (const float*)d_in[5];
  const float* bn1_v = (const float*)d_in[6];
  const float* w_off1 = (const float*)d_in[7];
  const float* w_off2 = (const float*)d_in[8];
  const float* b_off2 = (const float*)d_in[9];
  const float* w_mlp1 = (const float*)d_in[10];
  const float* bn2_g = (const float*)d_in[11];
  const float* bn2_b = (const float*)d_in[12];
  const float* bn2_m = (const float*)d_in[13];
  const float* bn2_v = (const float*)d_in[14];
  const float* w_mlp2 = (const float*)d_in[15];

  char* ws = (char*)d_ws;
  // workspace layout (48.9 MB total)
  u16* wa_bf = (u16*)(ws + 0);              // 256*256*2   = 131072
  u16* w1_bf = (u16*)(ws + 131072);         // 128*256*2   = 65536
  u16* w2_bf = (u16*)(ws + 196608);         // 256*128*2   = 65536
  float* bias1 = (float*)(ws + 262144);     // 256*4
  float* bias2 = (float*)(ws + 263168);     // 128*4
  float* coords = (float*)(ws + 263680);    // 16*4096*2*4 = 524288
  u16* gbuf = (u16*)(ws + 787968);          // 16*256*4096*2 = 33554432
  u16* hbuf = (u16*)(ws + 34342400);        // 16*128*4096*2 = 16777216
  // end: 51119616 bytes

  prep_weights<<<256, 256, 0, stream>>>(
      w_align, bn1_g, bn1_b, bn1_m, bn1_v,
      w_mlp1, bn2_g, bn2_b, bn2_m, bn2_v, w_mlp2,
      wa_bf, w1_bf, w2_bf, bias1, bias2);

  offsets_kernel<<<dim3(4, 4, 16), 256, 0, stream>>>(
      x_local, w_off1, w_off2, b_off2, coords);

  // g = BN1(W_align @ x_guide)  [bf16]
  gemm_k<256, false, 0><<<dim3(32, 2, 16), 256, 0, stream>>>(
      wa_bf, x_guide, gbuf, bias1, nullptr, nullptr, nullptr);

  // h = GELU(BN2(W1 @ x_local)) [bf16]
  gemm_k<256, false, 1><<<dim3(32, 1, 16), 256, 0, stream>>>(
      w1_bf, x_local, hbuf, bias2, nullptr, nullptr, nullptr);

  // out = SiLU(sample(g) + W2 @ h) [f32]
  gemm_k<128, true, 2><<<dim3(32, 2, 16), 256, 0, stream>>>(
      w2_bf, hbuf, nullptr, nullptr, gbuf, coords, (float*)d_out);
}

// Round 2
// 137.346 us; speedup vs baseline: 1.9379x; 1.9379x over previous
//
#include <hip/hip_runtime.h>

typedef unsigned short u16;
typedef __bf16 bf16x8 __attribute__((ext_vector_type(8)));
typedef float f32x4 __attribute__((ext_vector_type(4)));
typedef u16 u16x4 __attribute__((ext_vector_type(4)));
typedef u16 u16x8 __attribute__((ext_vector_type(8)));

#define EPS 1e-5f

__device__ __forceinline__ u16 f2bf(float f) {
  unsigned u = __builtin_bit_cast(unsigned, f);
  u += 0x7FFFu + ((u >> 16) & 1u);   // RNE
  return (u16)(u >> 16);
}
__device__ __forceinline__ float bf2f(u16 h) {
  unsigned u = ((unsigned)h) << 16;
  return __builtin_bit_cast(float, u);
}

// ---------------- weight prep: fold BN scale into bf16 weights ----------------
__global__ void prep_weights(
    const float* __restrict__ wa, const float* __restrict__ g1, const float* __restrict__ b1,
    const float* __restrict__ m1, const float* __restrict__ v1,
    const float* __restrict__ w1, const float* __restrict__ g2, const float* __restrict__ b2,
    const float* __restrict__ m2, const float* __restrict__ v2,
    const float* __restrict__ w2,
    u16* __restrict__ wa_o, u16* __restrict__ w1_o, u16* __restrict__ w2_o,
    float* __restrict__ bias1, float* __restrict__ bias2) {
  int t = blockIdx.x * 256 + threadIdx.x;
  if (t < 256 * 256) {
    int m = t >> 8;
    float s = g1[m] / sqrtf(v1[m] + EPS);
    wa_o[t] = f2bf(wa[t] * s);
  }
  if (t < 128 * 256) {
    int m = t >> 8;
    float s = g2[m] / sqrtf(v2[m] + EPS);
    w1_o[t] = f2bf(w1[t] * s);
  }
  if (t < 256 * 128) w2_o[t] = f2bf(w2[t]);
  if (t < 256) bias1[t] = b1[t] - m1[t] * (g1[t] / sqrtf(v1[t] + EPS));
  if (t < 128) bias2[t] = b2[t] - m2[t] * (g2[t] / sqrtf(v2[t] + EPS));
}

// ---------------- grouped 3x3 conv + SiLU -> s[b][q][p] ----------------
// grid = (band=4, q=64, b=16) = 4096 blocks, 256 threads. One barrier per block.
__global__ __launch_bounds__(256) void gconv_kernel(
    const float* __restrict__ xl, const float* __restrict__ w1,
    float* __restrict__ sbuf) {
  __shared__ float tile[4][18][66];
  const int tid = threadIdx.x;
  const int band = blockIdx.x;   // 16-row band
  const int q = blockIdx.y;
  const int b = blockIdx.z;
  const float* xb = xl + ((size_t)b * 256 + 4 * q) * 4096;
  for (int i = tid; i < 4 * 18 * 66; i += 256) {
    int ci = i / (18 * 66);
    int rem = i - ci * (18 * 66);
    int r = rem / 66, c = rem - r * 66;
    int gy = band * 16 - 1 + r, gx = c - 1;
    float v = 0.f;
    if ((unsigned)gy < 64u && (unsigned)gx < 64u)
      v = xb[(size_t)ci * 4096 + gy * 64 + gx];
    tile[ci][r][c] = v;
  }
  // weights are wave-uniform (q per block) -> scalar loads
  float wq[36];
#pragma unroll
  for (int i = 0; i < 36; ++i) wq[i] = w1[q * 36 + i];
  __syncthreads();
  const int c = tid & 63, r0 = tid >> 6;  // column, row-group
  float* sp = sbuf + ((size_t)(b * 64 + q)) * 4096 + band * 1024;
#pragma unroll
  for (int k = 0; k < 4; ++k) {
    int r = r0 * 4 + k;  // rows 0..15 within band
    float s = 0.f;
#pragma unroll
    for (int ci = 0; ci < 4; ++ci)
#pragma unroll
      for (int dy = 0; dy < 3; ++dy)
#pragma unroll
        for (int dx = 0; dx < 3; ++dx)
          s += wq[ci * 9 + dy * 3 + dx] * tile[ci][r + dy][c + dx];
    sp[r * 64 + c] = s / (1.f + __expf(-s));  // SiLU
  }
}

// ---------------- 1x1 conv over groups -> sample coords ----------------
// grid = (16, 16) = 256 blocks, 256 threads; thread = one pixel of one image.
__global__ __launch_bounds__(256) void coords_kernel(
    const float* __restrict__ sbuf, const float* __restrict__ w2,
    const float* __restrict__ b2, float* __restrict__ coords) {
  __shared__ float sw2[128];
  const int tid = threadIdx.x;
  if (tid < 128) sw2[tid] = w2[tid];
  __syncthreads();
  const int b = blockIdx.y;
  const int p = blockIdx.x * 256 + tid;
  const float* sp = sbuf + (size_t)b * 64 * 4096 + p;
  float ax = 0.f, ay = 0.f;
#pragma unroll 8
  for (int q = 0; q < 64; ++q) {
    float v = sp[(size_t)q * 4096];
    ax += sw2[q] * v;
    ay += sw2[64 + q] * v;
  }
  int y = p >> 6, x = p & 63;
  // ix = 64x/63 + off_x - 0.5  (align_corners=False, grid scale 2/64)
  float ix = (64.f / 63.f) * (float)x + ax + b2[0] - 0.5f;
  float iy = (64.f / 63.f) * (float)y + ay + b2[1] - 0.5f;
  ((float2*)coords)[(size_t)b * 4096 + p] = make_float2(ix, iy);
}

// ---------------- templated MFMA GEMM ----------------
// BM=BN=128, BK=32, 256 threads = 4 waves, each wave owns a 64x64 quadrant (4x4 frags of 16x16x32).
// A: [Mtot][K] bf16 (pre-scaled weights). B: per-batch [K][4096] (f32 or bf16) -> LDS transposed [n][k].
// EPI 0: +bias1 -> g (bf16). EPI 1: +bias2, GELU -> h (bf16). EPI 2: bilinear-sample(g) + acc, SiLU -> out f32.
template <int K, bool B_IS_BF16, int EPI>
__global__ __launch_bounds__(256, 2) void gemm_k(
    const u16* __restrict__ A, const void* __restrict__ Bsrc,
    u16* __restrict__ OutBf, const float* __restrict__ bias,
    const u16* __restrict__ g, const float* __restrict__ coords,
    float* __restrict__ out_f) {
  __shared__ u16 Al[128][40];  // 32 data + 8 pad (row = 80B, 16B-aligned)
  __shared__ u16 Bl[128][40];  // [n][k]
  const int tid = threadIdx.x;
  const int b = blockIdx.z;
  const int n0 = blockIdx.x * 128;
  const int m0 = blockIdx.y * 128;
  const int wave = tid >> 6, lane = tid & 63;
  const int wr = wave >> 1, wc = wave & 1;
  const int lr = lane & 15, kg = lane >> 4;

  f32x4 acc[4][4] = {};

  const float* Bf = (const float*)Bsrc + (size_t)b * K * 4096;
  const u16* Bh = (const u16*)Bsrc + (size_t)b * K * 4096;

  for (int kt = 0; kt < K / 32; ++kt) {
    // ---- stage A (bf16, already converted) : 512 chunks of 8 bf16 ----
#pragma unroll
    for (int c = 0; c < 2; ++c) {
      int ch = tid + c * 256;
      int m = ch >> 2, pos = (ch & 3) * 8;
      u16x8 v = *(const u16x8*)(A + (size_t)(m0 + m) * K + kt * 32 + pos);
      *(u16x8*)&Al[m][pos] = v;
    }
    // ---- stage B with transpose (4x4 micro-tile per thread) ----
    {
      int nq = tid & 31, kq = tid >> 5;  // nq in [0,32), kq in [0,8)
      int kb = kt * 32 + kq * 4;
      int nb = n0 + nq * 4;
      if (B_IS_BF16) {
        u16x4 r[4];
#pragma unroll
        for (int i = 0; i < 4; ++i)
          r[i] = *(const u16x4*)(Bh + (size_t)(kb + i) * 4096 + nb);
#pragma unroll
        for (int j = 0; j < 4; ++j) {
          u16x4 w = {r[0][j], r[1][j], r[2][j], r[3][j]};
          *(u16x4*)&Bl[nq * 4 + j][kq * 4] = w;
        }
      } else {
        f32x4 r[4];
#pragma unroll
        for (int i = 0; i < 4; ++i)
          r[i] = *(const f32x4*)(Bf + (size_t)(kb + i) * 4096 + nb);
#pragma unroll
        for (int j = 0; j < 4; ++j) {
          u16x4 w = {f2bf(r[0][j]), f2bf(r[1][j]), f2bf(r[2][j]), f2bf(r[3][j])};
          *(u16x4*)&Bl[nq * 4 + j][kq * 4] = w;
        }
      }
    }
    __syncthreads();
    bf16x8 af[4], bfr[4];
#pragma unroll
    for (int i = 0; i < 4; ++i) {
      af[i] = *(const bf16x8*)&Al[wr * 64 + i * 16 + lr][kg * 8];
      bfr[i] = *(const bf16x8*)&Bl[wc * 64 + i * 16 + lr][kg * 8];
    }
#pragma unroll
    for (int i = 0; i < 4; ++i)
#pragma unroll
      for (int j = 0; j < 4; ++j)
        acc[i][j] = __builtin_amdgcn_mfma_f32_16x16x32_bf16(af[i], bfr[j], acc[i][j], 0, 0, 0);
    __syncthreads();
  }

  // ---- epilogue ----
  if constexpr (EPI == 0 || EPI == 1) {
    const int MT = (EPI == 0) ? 256 : 128;
    u16* O = OutBf + (size_t)b * MT * 4096;
#pragma unroll
    for (int i = 0; i < 4; ++i) {
      int rb = m0 + wr * 64 + i * 16 + kg * 4;
      f32x4 b4 = *(const f32x4*)(bias + rb);
#pragma unroll
      for (int j = 0; j < 4; ++j) {
        int col = n0 + wc * 64 + j * 16 + lr;
#pragma unroll
        for (int e = 0; e < 4; ++e) {
          float v = acc[i][j][e] + b4[e];
          if (EPI == 1) v = 0.5f * v * (1.f + erff(v * 0.70710678118f));  // exact GELU
          O[(size_t)(rb + e) * 4096 + col] = f2bf(v);
        }
      }
    }
  } else {
    const u16* gb = g + (size_t)b * 256 * 4096;
    float* Ob = out_f + (size_t)b * 256 * 4096;
#pragma unroll
    for (int j = 0; j < 4; ++j) {
      int col = n0 + wc * 64 + j * 16 + lr;
      float2 cd = ((const float2*)coords)[(size_t)b * 4096 + col];
      float ix = cd.x, iy = cd.y;
      float x0f = floorf(ix), y0f = floorf(iy);
      int x0 = (int)x0f, y0 = (int)y0f;
      float wx1 = ix - x0f, wx0 = 1.f - wx1;
      float wy1 = iy - y0f, wy0 = 1.f - wy1;
      bool vx0 = (unsigned)x0 < 64u, vx1 = (unsigned)(x0 + 1) < 64u;
      bool vy0 = (unsigned)y0 < 64u, vy1 = (unsigned)(y0 + 1) < 64u;
      int x0c = min(max(x0, 0), 63), x1c = min(max(x0 + 1, 0), 63);
      int y0c = min(max(y0, 0), 63), y1c = min(max(y0 + 1, 0), 63);
      float w00 = (vx0 && vy0) ? wx0 * wy0 : 0.f;
      float w10 = (vx1 && vy0) ? wx1 * wy0 : 0.f;
      float w01 = (vx0 && vy1) ? wx0 * wy1 : 0.f;
      float w11 = (vx1 && vy1) ? wx1 * wy1 : 0.f;
      int i00 = y0c * 64 + x0c, i10 = y0c * 64 + x1c;
      int i01 = y1c * 64 + x0c, i11 = y1c * 64 + x1c;
#pragma unroll
      for (int i = 0; i < 4; ++i) {
        int rb = m0 + wr * 64 + i * 16 + kg * 4;
#pragma unroll
        for (int e = 0; e < 4; ++e) {
          int c = rb + e;
          const u16* gc = gb + (size_t)c * 4096;
          float samp = w00 * bf2f(gc[i00]) + w10 * bf2f(gc[i10]) +
                       w01 * bf2f(gc[i01]) + w11 * bf2f(gc[i11]);
          float v = samp + acc[i][j][e];
          Ob[(size_t)c * 4096 + col] = v / (1.f + __expf(-v));  // SiLU
        }
      }
    }
  }
}

// ---------------- launch ----------------
extern "C" void kernel_launch(void* const* d_in, const int* in_sizes, int n_in,
                              void* d_out, int out_size, void* d_ws, size_t ws_size,
                              hipStream_t stream) {
  const float* x_local = (const float*)d_in[0];
  const float* x_guide = (const float*)d_in[1];
  const float* w_align = (const float*)d_in[2];
  const float* bn1_g = (const float*)d_in[3];
  const float* bn1_b = (const float*)d_in[4];
  const float* bn1_m = (const float*)d_in[5];
  const float* bn1_v = (const float*)d_in[6];
  const float* w_off1 = (const float*)d_in[7];
  const float* w_off2 = (const float*)d_in[8];
  const float* b_off2 = (const float*)d_in[9];
  const float* w_mlp1 = (const float*)d_in[10];
  const float* bn2_g = (const float*)d_in[11];
  const float* bn2_b = (const float*)d_in[12];
  const float* bn2_m = (const float*)d_in[13];
  const float* bn2_v = (const float*)d_in[14];
  const float* w_mlp2 = (const float*)d_in[15];

  char* ws = (char*)d_ws;
  // workspace layout
  u16* wa_bf = (u16*)(ws + 0);              // 256*256*2   = 131072
  u16* w1_bf = (u16*)(ws + 131072);         // 128*256*2   = 65536
  u16* w2_bf = (u16*)(ws + 196608);         // 256*128*2   = 65536
  float* bias1 = (float*)(ws + 262144);     // 256*4
  float* bias2 = (float*)(ws + 263168);     // 128*4
  float* coords = (float*)(ws + 263680);    // 16*4096*2*4 = 524288
  u16* gbuf = (u16*)(ws + 787968);          // 16*256*4096*2 = 33554432
  u16* hbuf = (u16*)(ws + 34342400);        // 16*128*4096*2 = 16777216
  // sbuf (16*64*4096*4 = 16.78 MB) aliases gbuf's region: it is fully consumed
  // by coords_kernel before gemm<EPI0> writes gbuf (same stream, ordered).
  float* sbuf = (float*)gbuf;

  prep_weights<<<256, 256, 0, stream>>>(
      w_align, bn1_g, bn1_b, bn1_m, bn1_v,
      w_mlp1, bn2_g, bn2_b, bn2_m, bn2_v, w_mlp2,
      wa_bf, w1_bf, w2_bf, bias1, bias2);

  // grouped conv + SiLU -> sbuf[b][q][p]
  gconv_kernel<<<dim3(4, 64, 16), 256, 0, stream>>>(x_local, w_off1, sbuf);

  // 1x1 conv over groups -> coords
  coords_kernel<<<dim3(16, 16), 256, 0, stream>>>(sbuf, w_off2, b_off2, coords);

  // g = BN1(W_align @ x_guide)  [bf16]
  gemm_k<256, false, 0><<<dim3(32, 2, 16), 256, 0, stream>>>(
      wa_bf, x_guide, gbuf, bias1, nullptr, nullptr, nullptr);

  // h = GELU(BN2(W1 @ x_local)) [bf16]
  gemm_k<256, false, 1><<<dim3(32, 1, 16), 256, 0, stream>>>(
      w1_bf, x_local, hbuf, bias2, nullptr, nullptr, nullptr);

  // out = SiLU(sample(g) + W2 @ h) [f32]
  gemm_k<128, true, 2><<<dim3(32, 2, 16), 256, 0, stream>>>(
      w2_bf, hbuf, nullptr, nullptr, gbuf, coords, (float*)d_out);
}